// Round 7
// baseline (1574.008 us; speedup 1.0000x reference)
//
#include <hip/hip_runtime.h>

#define N_NODES 50000
#define N_EDGES 1600000

typedef _Float16 f16x8 __attribute__((ext_vector_type(8)));
typedef float f32x4 __attribute__((ext_vector_type(4)));

__device__ __forceinline__ float fast_rcp(float v) {
#if __has_builtin(__builtin_amdgcn_rcpf)
    return __builtin_amdgcn_rcpf(v);
#else
    return __frcp_rn(v);
#endif
}

// ---------------------------------------------------------------------------
// prep_weights: f16 weight images, transposed ([n][k]) and 16B-chunk
// XOR-swizzled (chunk' = chunk ^ (n&7)).
// W1img: [128][64] (Wf1 50x128, K zero-padded to 64).
// W2img/Wi2fimg/Wm1img/Wm2img: [128][128] from Wf2/W_in2f/Wm1/Wm2.
// ---------------------------------------------------------------------------
__global__ void prep_weights(const float* __restrict__ Wf1,
                             const float* __restrict__ Wf2,
                             const float* __restrict__ W_in2f,
                             const float* __restrict__ Wm1,
                             const float* __restrict__ Wm2,
                             _Float16* __restrict__ W1img,
                             _Float16* __restrict__ W2img,
                             _Float16* __restrict__ Wi2fimg,
                             _Float16* __restrict__ Wm1img,
                             _Float16* __restrict__ Wm2img) {
    int i = blockIdx.x * 256 + threadIdx.x;
    if (i < 8192) {
        int n = i >> 6, k = i & 63;
        float v = (k < 50) ? Wf1[k * 128 + n] : 0.0f;
        W1img[n * 64 + (((k >> 3) ^ (n & 7)) << 3) + (k & 7)] = (_Float16)v;
    }
    if (i < 16384) {
        int n = i >> 7, k = i & 127;
        int off = n * 128 + (((k >> 3) ^ (n & 7)) << 3) + (k & 7);
        int src = k * 128 + n;
        W2img[off]   = (_Float16)Wf2[src];
        Wi2fimg[off] = (_Float16)W_in2f[src];
        Wm1img[off]  = (_Float16)Wm1[src];
        Wm2img[off]  = (_Float16)Wm2[src];
    }
}

// ---------------------------------------------------------------------------
// fused_hv_hist: blocks [0,391) do hv = feat @ W_in2f via MFMA (f16 in,
// fp32 acc, f16 store); blocks [391, 391+3125) do the dst histogram.
// ---------------------------------------------------------------------------
__global__ __launch_bounds__(512) void fused_hv_hist(
        const float* __restrict__ feat, const _Float16* __restrict__ Wi2fimg,
        _Float16* __restrict__ hvh,
        const int* __restrict__ dstv, int* __restrict__ cnt) {
    const int b = blockIdx.x;
    const int tid = threadIdx.x;
    if (b < 391) {
        const int lane = tid & 63, wv = tid >> 6;
        const int l15 = lane & 15, q = lane >> 4;
        const int row0 = b * 128;
        int ar = row0 + wv * 16 + l15;
        if (ar > N_NODES - 1) ar = N_NODES - 1;
        const float* arow = feat + (long)ar * 128;
        f16x8 a[4];
        #pragma unroll
        for (int ks = 0; ks < 4; ++ks) {
            const float* p = arow + ks * 32 + q * 8;
            float2 u0 = *(const float2*)(p + 0);
            float2 u1 = *(const float2*)(p + 2);
            float2 u2 = *(const float2*)(p + 4);
            float2 u3 = *(const float2*)(p + 6);
            a[ks][0] = (_Float16)u0.x; a[ks][1] = (_Float16)u0.y;
            a[ks][2] = (_Float16)u1.x; a[ks][3] = (_Float16)u1.y;
            a[ks][4] = (_Float16)u2.x; a[ks][5] = (_Float16)u2.y;
            a[ks][6] = (_Float16)u3.x; a[ks][7] = (_Float16)u3.y;
        }
        f32x4 acc[8];
        for (int nb = 0; nb < 8; ++nb) acc[nb] = (f32x4){0.f, 0.f, 0.f, 0.f};
        #pragma unroll
        for (int ks = 0; ks < 4; ++ks) {
            int c = ks * 4 + q;
            #pragma unroll
            for (int nb = 0; nb < 8; ++nb) {
                int n = nb * 16 + l15;
                f16x8 bf = *(const f16x8*)&Wi2fimg[n * 128 + ((c ^ (n & 7)) << 3)];
                acc[nb] = __builtin_amdgcn_mfma_f32_16x16x32_f16(a[ks], bf, acc[nb], 0, 0, 0);
            }
        }
        #pragma unroll
        for (int nb = 0; nb < 8; ++nb)
            #pragma unroll
            for (int r = 0; r < 4; ++r) {
                int orow = row0 + wv * 16 + q * 4 + r;
                if (orow < N_NODES)
                    hvh[(long)orow * 128 + nb * 16 + l15] = (_Float16)acc[nb][r];
            }
    } else {
        int e = (b - 391) * 512 + tid;
        if (e < N_EDGES) atomicAdd(&cnt[dstv[e]], 1);
    }
}

// ---------------------------------------------------------------------------
// Counting sort by dst: hist (fused above) -> 3-kernel shuffle scan -> scatter.
// ---------------------------------------------------------------------------
__global__ __launch_bounds__(1024) void scan_reduce(const int* __restrict__ cnt,
                                                    int* __restrict__ bsum) {
    __shared__ int ws[16];
    int tid = threadIdx.x, lane = tid & 63;
    int i = blockIdx.x * 1024 + tid;
    int x = (i < N_NODES) ? cnt[i] : 0;
    for (int o = 32; o > 0; o >>= 1) x += __shfl_down(x, o);
    if (lane == 0) ws[tid >> 6] = x;
    __syncthreads();
    if (tid == 0) {
        int s = 0;
        for (int w = 0; w < 16; ++w) s += ws[w];
        bsum[blockIdx.x] = s;
    }
}

__global__ void scan_top(int* __restrict__ bsum) {   // 49 block sums, serial
    if (threadIdx.x == 0) {
        int s = 0;
        for (int b = 0; b < 49; ++b) { int v = bsum[b]; bsum[b] = s; s += v; }
    }
}

__global__ __launch_bounds__(1024) void scan_apply(int* __restrict__ cnt,
                                                   const int* __restrict__ bsum) {
    __shared__ int ws[16], wo[16];
    int tid = threadIdx.x, lane = tid & 63, wid = tid >> 6;
    int i = blockIdx.x * 1024 + tid;
    int x = (i < N_NODES) ? cnt[i] : 0;
    int incl = x;
    for (int o = 1; o < 64; o <<= 1) {
        int y = __shfl_up(incl, o);
        if (lane >= o) incl += y;
    }
    if (lane == 63) ws[wid] = incl;
    __syncthreads();
    if (tid == 0) {
        int s = 0;
        for (int w = 0; w < 16; ++w) { wo[w] = s; s += ws[w]; }
    }
    __syncthreads();
    if (i < N_NODES) cnt[i] = bsum[blockIdx.x] + wo[wid] + incl - x;  // exclusive
}

__global__ void scatter_kernel(const int* __restrict__ dstv,
                               const int* __restrict__ srcv,
                               const float* __restrict__ rij,
                               int* __restrict__ cursor,
                               int4* __restrict__ meta) {
    int e = blockIdx.x * 256 + threadIdx.x;
    if (e < N_EDGES) {
        int d = dstv[e];
        int pos = atomicAdd(&cursor[d], 1);
        meta[pos] = make_int4(e, srcv[e], d, __float_as_int(rij[e]));
    }
}

// ---------------------------------------------------------------------------
// edge_kernel, 512 threads (8 waves x 16 rows), dst-sorted edges.
//   B-fragments for BOTH GEMMs read directly from global weight images
//   (48 KB total, L1/L2-hot; same pattern as fused_hv_hist) -> no LDS
//   weight staging, no B-read bank conflicts (rows were 128/256B apart =
//   all bank-0 aligned = ~8-way conflicts).
//   LDS = sTM [128][128] f16 (sT then sM overlay, 16B-chunk XOR swizzle)
//   + sMeta = 34 KB -> 4 blocks/CU (was 2).
//   sTM rows are WAVE-PRIVATE (wave w touches rows [16w,16w+16) only, in
//   program order: epi1-write -> GEMM2-read -> epi2-write -> reduction-read)
//   so ONE __syncthreads (after sMeta stage) suffices; waves pipeline freely.
//   pf gathers issued after GEMM1 so they drain under epilogue1, not under
//   GEMM1's global B-loads (vmcnt is FIFO).
// MFMA 16x16x32_f16 layouts (verified): A: m=lane&15, k=(lane>>4)*8+j;
//   D: row=(lane>>4)*4+r, col=lane&15.
// ---------------------------------------------------------------------------
__global__ __launch_bounds__(512, 8) void edge_kernel(
        const float* __restrict__ fij, const _Float16* __restrict__ hvh,
        const _Float16* __restrict__ W1img, const _Float16* __restrict__ W2img,
        const float* __restrict__ bf1, const float* __restrict__ bf2,
        const int4* __restrict__ meta, float* __restrict__ agg) {
    __shared__ __align__(16) _Float16 sTM[128 * 128];   // 32 KB
    __shared__ __align__(16) int4 sMeta[128];           //  2 KB

    const int tid = threadIdx.x;
    const int lane = tid & 63;
    const int wv = tid >> 6;          // 0..7 -> rows [wv*16, wv*16+16)
    const int l15 = lane & 15;
    const int q = lane >> 4;
    const int e0 = blockIdx.x * 128;

    // ---- early: this lane's A-frag row + direct global->reg fij loads ----
    const int arow = wv * 16 + l15;
    const int eid = meta[e0 + arow].x;
    const float* frow = fij + (long)eid * 50;
    float2 p0 = *(const float2*)(frow + q * 8 + 0);
    float2 p1 = *(const float2*)(frow + q * 8 + 2);
    float2 p2 = *(const float2*)(frow + q * 8 + 4);
    float2 p3 = *(const float2*)(frow + q * 8 + 6);
    const int kb = 32 + q * 8;
    float2 z2 = make_float2(0.f, 0.f);
    float2 p4 = (kb + 1 < 50) ? *(const float2*)(frow + kb + 0) : z2;
    float2 p5 = (kb + 3 < 50) ? *(const float2*)(frow + kb + 2) : z2;
    float2 p6 = (kb + 5 < 50) ? *(const float2*)(frow + kb + 4) : z2;
    float2 p7 = (kb + 7 < 50) ? *(const float2*)(frow + kb + 6) : z2;
    f16x8 a0, a1;
    a0[0] = (_Float16)p0.x; a0[1] = (_Float16)p0.y;
    a0[2] = (_Float16)p1.x; a0[3] = (_Float16)p1.y;
    a0[4] = (_Float16)p2.x; a0[5] = (_Float16)p2.y;
    a0[6] = (_Float16)p3.x; a0[7] = (_Float16)p3.y;
    a1[0] = (_Float16)p4.x; a1[1] = (_Float16)p4.y;
    a1[2] = (_Float16)p5.x; a1[3] = (_Float16)p5.y;
    a1[4] = (_Float16)p6.x; a1[5] = (_Float16)p6.y;
    a1[6] = (_Float16)p7.x; a1[7] = (_Float16)p7.y;

    // ---- stage sMeta + biases ----
    if (tid < 128) sMeta[tid] = meta[e0 + tid];
    float b1v[8], b2v[8];
    for (int nb = 0; nb < 8; ++nb) {
        b1v[nb] = bf1[nb * 16 + l15];
        b2v[nb] = bf2[nb * 16 + l15];
    }
    __syncthreads();   // the ONLY barrier: sMeta visible to all waves

    // ---- GEMM1: [16 x 64] x [64 x 128] per wave; B from global (L1-hot) --
    f32x4 acc[8];
    for (int nb = 0; nb < 8; ++nb) acc[nb] = (f32x4){0.f, 0.f, 0.f, 0.f};
    #pragma unroll
    for (int nb = 0; nb < 8; ++nb) {
        int n = nb * 16 + l15;
        f16x8 b = *(const f16x8*)&W1img[n * 64 + ((q ^ (n & 7)) << 3)];
        acc[nb] = __builtin_amdgcn_mfma_f32_16x16x32_f16(a0, b, acc[nb], 0, 0, 0);
    }
    #pragma unroll
    for (int nb = 0; nb < 8; ++nb) {
        int n = nb * 16 + l15;
        f16x8 b = *(const f16x8*)&W1img[n * 64 + (((4 + q) ^ (n & 7)) << 3)];
        acc[nb] = __builtin_amdgcn_mfma_f32_16x16x32_f16(a1, b, acc[nb], 0, 0, 0);
    }

    // ---- pf: hv gathers for the reduction (drain under epi1/GEMM2) ----
    const int col2 = tid & 63;
    const int rseg0 = wv * 16;
    unsigned int pf[16];
    #pragma unroll
    for (int i = 0; i < 16; ++i) {
        long srcn = sMeta[rseg0 + i].y;            // wave-uniform LDS broadcast
        pf[i] = *(const unsigned int*)(hvh + srcn * 128 + col2 * 2);
    }

    // ---- epilogue1: t = swish(x1 + bf1) -> sTM (swizzled, wave-private) --
    #pragma unroll
    for (int nb = 0; nb < 8; ++nb)
        #pragma unroll
        for (int r = 0; r < 4; ++r) {
            float x = acc[nb][r] + b1v[nb];
            float tt = x * fast_rcp(1.0f + __expf(-x));
            int row = wv * 16 + q * 4 + r;
            int col = nb * 16 + l15;
            sTM[row * 128 + (((col >> 3) ^ (row & 7)) << 3) + (col & 7)] = (_Float16)tt;
        }

    // ---- GEMM2: [16 x 128] x [128 x 128] per wave; B from global ----
    for (int nb = 0; nb < 8; ++nb) acc[nb] = (f32x4){0.f, 0.f, 0.f, 0.f};
    {
        const int row = wv * 16 + l15;
        const _Float16* abase = &sTM[row * 128];
        #pragma unroll
        for (int ks = 0; ks < 4; ++ks) {
            int c = ks * 4 + q;
            f16x8 a = *(const f16x8*)&abase[(c ^ (row & 7)) << 3];
            #pragma unroll
            for (int nb = 0; nb < 8; ++nb) {
                int n = nb * 16 + l15;
                f16x8 b = *(const f16x8*)&W2img[n * 128 + ((c ^ (n & 7)) << 3)];
                acc[nb] = __builtin_amdgcn_mfma_f32_16x16x32_f16(a, b, acc[nb], 0, 0, 0);
            }
        }
    }

    // ---- epilogue2: he = (x2+bf2)*C -> sTM overlay (same swizzle) ----
    #pragma unroll
    for (int r = 0; r < 4; ++r) {
        int row = wv * 16 + q * 4 + r;
        float rv = __int_as_float(sMeta[row].w);
        float Cr = (rv < 5.0f) ? 0.5f * (__cosf(0.6283185307179586f * rv) + 1.0f) : 0.0f;
        #pragma unroll
        for (int nb = 0; nb < 8; ++nb) {
            int col = nb * 16 + l15;
            sTM[row * 128 + (((col >> 3) ^ (row & 7)) << 3) + (col & 7)] =
                (_Float16)((acc[nb][r] + b2v[nb]) * Cr);
        }
    }

    // ---- reduction: per-wave 16 rows x 64 col-pairs; hv from pf regs ----
    {
        float run0 = 0.0f, run1 = 0.0f;
        int cur = sMeta[rseg0].z;
        #pragma unroll
        for (int i = 0; i < 16; ++i) {
            int r = rseg0 + i;
            int d = sMeta[r].z;                 // wave-uniform broadcast
            if (d != cur) {                     // wave-uniform branch
                atomicAdd(&agg[cur * 128 + col2 * 2], run0);
                atomicAdd(&agg[cur * 128 + col2 * 2 + 1], run1);
                run0 = 0.0f; run1 = 0.0f; cur = d;
            }
            union { unsigned int u; _Float16 h[2]; } hv2; hv2.u = pf[i];
            union { unsigned int u; _Float16 h[2]; } m2;
            m2.u = *(const unsigned int*)
                &sTM[r * 128 + ((((col2 >> 2) ^ (r & 7)) << 3) + ((col2 & 3) << 1))];
            run0 += (float)hv2.h[0] * (float)m2.h[0];
            run1 += (float)hv2.h[1] * (float)m2.h[1];
        }
        atomicAdd(&agg[cur * 128 + col2 * 2], run0);
        atomicAdd(&agg[cur * 128 + col2 * 2 + 1], run1);
    }
}

// ---------------------------------------------------------------------------
// out_kernel (MFMA): out = swish(agg @ Wm1 + bm1) @ Wm2 + bm2.
// ---------------------------------------------------------------------------
__global__ __launch_bounds__(512) void out_kernel(const float* __restrict__ agg,
                                                  const _Float16* __restrict__ Wm1img,
                                                  const float* __restrict__ bm1,
                                                  const _Float16* __restrict__ Wm2img,
                                                  const float* __restrict__ bm2,
                                                  float* __restrict__ out) {
    __shared__ __align__(16) _Float16 sT[128 * 128];
    const int tid = threadIdx.x, lane = tid & 63, wv = tid >> 6;
    const int l15 = lane & 15, q = lane >> 4;
    const int row0 = blockIdx.x * 128;
    int ar = row0 + wv * 16 + l15;
    if (ar > N_NODES - 1) ar = N_NODES - 1;
    const float* arow = agg + (long)ar * 128;
    f16x8 a[4];
    #pragma unroll
    for (int ks = 0; ks < 4; ++ks) {
        const float* p = arow + ks * 32 + q * 8;
        float2 u0 = *(const float2*)(p + 0);
        float2 u1 = *(const float2*)(p + 2);
        float2 u2 = *(const float2*)(p + 4);
        float2 u3 = *(const float2*)(p + 6);
        a[ks][0] = (_Float16)u0.x; a[ks][1] = (_Float16)u0.y;
        a[ks][2] = (_Float16)u1.x; a[ks][3] = (_Float16)u1.y;
        a[ks][4] = (_Float16)u2.x; a[ks][5] = (_Float16)u2.y;
        a[ks][6] = (_Float16)u3.x; a[ks][7] = (_Float16)u3.y;
    }
    float b1v[8], b2v[8];
    for (int nb = 0; nb < 8; ++nb) {
        b1v[nb] = bm1[nb * 16 + l15];
        b2v[nb] = bm2[nb * 16 + l15];
    }
    f32x4 acc[8];
    for (int nb = 0; nb < 8; ++nb) acc[nb] = (f32x4){0.f, 0.f, 0.f, 0.f};
    #pragma unroll
    for (int ks = 0; ks < 4; ++ks) {
        int c = ks * 4 + q;
        #pragma unroll
        for (int nb = 0; nb < 8; ++nb) {
            int n = nb * 16 + l15;
            f16x8 bf = *(const f16x8*)&Wm1img[n * 128 + ((c ^ (n & 7)) << 3)];
            acc[nb] = __builtin_amdgcn_mfma_f32_16x16x32_f16(a[ks], bf, acc[nb], 0, 0, 0);
        }
    }
    #pragma unroll
    for (int nb = 0; nb < 8; ++nb)
        #pragma unroll
        for (int r = 0; r < 4; ++r) {
            float x = acc[nb][r] + b1v[nb];
            float tt = x * fast_rcp(1.0f + __expf(-x));
            int row = wv * 16 + q * 4 + r;
            int col = nb * 16 + l15;
            sT[row * 128 + (((col >> 3) ^ (row & 7)) << 3) + (col & 7)] = (_Float16)tt;
        }
    __syncthreads();
    for (int nb = 0; nb < 8; ++nb) acc[nb] = (f32x4){0.f, 0.f, 0.f, 0.f};
    {
        const int rowA = wv * 16 + l15;
        const _Float16* abase = &sT[rowA * 128];
        #pragma unroll
        for (int ks = 0; ks < 4; ++ks) {
            int c = ks * 4 + q;
            f16x8 a2 = *(const f16x8*)&abase[(c ^ (rowA & 7)) << 3];
            #pragma unroll
            for (int nb = 0; nb < 8; ++nb) {
                int n = nb * 16 + l15;
                f16x8 bf = *(const f16x8*)&Wm2img[n * 128 + ((c ^ (n & 7)) << 3)];
                acc[nb] = __builtin_amdgcn_mfma_f32_16x16x32_f16(a2, bf, acc[nb], 0, 0, 0);
            }
        }
    }
    #pragma unroll
    for (int nb = 0; nb < 8; ++nb)
        #pragma unroll
        for (int r = 0; r < 4; ++r) {
            int orow = row0 + wv * 16 + q * 4 + r;
            if (orow < N_NODES)
                out[(long)orow * 128 + nb * 16 + l15] = acc[nb][r] + b2v[nb];
        }
}

// ---------------------------------------------------------------------------
extern "C" void kernel_launch(void* const* d_in, const int* in_sizes, int n_in,
                              void* d_out, int out_size, void* d_ws, size_t ws_size,
                              hipStream_t stream) {
    const float* feat   = (const float*)d_in[0];
    const float* fij    = (const float*)d_in[1];
    const float* rij    = (const float*)d_in[2];
    const int*   srcv   = (const int*)d_in[3];
    const int*   dstv   = (const int*)d_in[4];
    const float* W_in2f = (const float*)d_in[5];
    const float* Wf1    = (const float*)d_in[6];
    const float* bf1    = (const float*)d_in[7];
    const float* Wf2    = (const float*)d_in[8];
    const float* bf2    = (const float*)d_in[9];
    const float* Wm1    = (const float*)d_in[10];
    const float* bm1    = (const float*)d_in[11];
    const float* Wm2    = (const float*)d_in[12];
    const float* bm2    = (const float*)d_in[13];
    float* out = (float*)d_out;

    char* ws = (char*)d_ws;
    float*    agg     = (float*)ws;                         // 25,600,000 B
    _Float16* hvh     = (_Float16*)(ws + 25600000);         // 12,800,000 B
    int4*     meta    = (int4*)(ws + 38400000);             // 25,600,000 B
    int*      cnt     = (int*)(ws + 64000000);              //    200,000 B
    int*      bsum    = (int*)(ws + 64200000);              //        256 B
    _Float16* W1img   = (_Float16*)(ws + 64200704);         //     16,384 B
    _Float16* W2img   = (_Float16*)(ws + 64217088);         //     32,768 B
    _Float16* Wi2fimg = (_Float16*)(ws + 64249856);         //     32,768 B
    _Float16* Wm1img  = (_Float16*)(ws + 64282624);         //     32,768 B
    _Float16* Wm2img  = (_Float16*)(ws + 64315392);         //     32,768 B

    hipMemsetAsync(agg, 0, (size_t)N_NODES * 128 * sizeof(float), stream);
    hipMemsetAsync(cnt, 0, (size_t)N_NODES * sizeof(int), stream);
    prep_weights<<<64, 256, 0, stream>>>(Wf1, Wf2, W_in2f, Wm1, Wm2,
                                         W1img, W2img, Wi2fimg, Wm1img, Wm2img);
    fused_hv_hist<<<391 + 3125, 512, 0, stream>>>(feat, Wi2fimg, hvh, dstv, cnt);
    scan_reduce<<<49, 1024, 0, stream>>>(cnt, bsum);
    scan_top<<<1, 64, 0, stream>>>(bsum);
    scan_apply<<<49, 1024, 0, stream>>>(cnt, bsum);
    scatter_kernel<<<(N_EDGES + 255) / 256, 256, 0, stream>>>(dstv, srcv, rij, cnt, meta);
    edge_kernel<<<12500, 512, 0, stream>>>(fij, hvh, W1img, W2img, bf1, bf2, meta, agg);
    out_kernel<<<391, 512, 0, stream>>>(agg, Wm1img, bm1, Wm2img, bm2, out);
}